// Round 1
// baseline (634.674 us; speedup 1.0000x reference)
//
#include <hip/hip_runtime.h>

// Problem constants
#define B_   8
#define NT_  512
#define NC_  2048
#define EMB_ 512
#define H_   8
// DK = DV = 64

typedef __attribute__((ext_vector_type(8))) short bf16x8;
typedef __attribute__((ext_vector_type(4))) float f32x4;

__device__ __forceinline__ unsigned short f2bf(float x) {
    unsigned u = __float_as_uint(x);
    u += 0x7fffu + ((u >> 16) & 1u);          // RNE
    return (unsigned short)(u >> 16);
}
__device__ __forceinline__ float b2f(unsigned short h) {
    return __uint_as_float(((unsigned)h) << 16);
}

// XOR-swizzled LDS tile index: rows of 64 bf16, 8-elem (16B) granules.
// granule' = granule ^ (row&7)  -> conflict-free b128 frag reads & stage writes.
__device__ __forceinline__ int swz(int row, int col) {
    return row * 64 + ((((col >> 3) ^ row) & 7) << 3) + (col & 7);
}

// Load an MFMA operand fragment (A-layout: elem j of lane L holds [rowbase + (L&15)][kq + (L>>4)*8 + j])
__device__ __forceinline__ bf16x8 ldfrag(const unsigned short* t, int rowbase, int kq) {
    int lane = threadIdx.x & 63;
    int m = rowbase + (lane & 15);
    int k = kq + ((lane >> 4) << 3);
    return *(const bf16x8*)(t + swz(m, k));
}

// Stage a 64-col x (NCH*32)-row bf16 tile into swizzled LDS from fp32 global.
template<int NCH>
__device__ __forceinline__ void stage_f32(unsigned short* tile, const float* src, int ld) {
    int tid = threadIdx.x;
#pragma unroll
    for (int i = 0; i < NCH; i++) {
        int ch  = tid + i * 256;
        int row = ch >> 3, c8 = ch & 7;
        const float4* p = (const float4*)(src + (size_t)row * ld + c8 * 8);
        float4 a = p[0], b = p[1];
        uint4 u;
        u.x = (unsigned)f2bf(a.x) | ((unsigned)f2bf(a.y) << 16);
        u.y = (unsigned)f2bf(a.z) | ((unsigned)f2bf(a.w) << 16);
        u.z = (unsigned)f2bf(b.x) | ((unsigned)f2bf(b.y) << 16);
        u.w = (unsigned)f2bf(b.z) | ((unsigned)f2bf(b.w) << 16);
        *(uint4*)(tile + row * 64 + (((c8 ^ row) & 7) << 3)) = u;
    }
}
// Same, from bf16 global.
template<int NCH>
__device__ __forceinline__ void stage_bf(unsigned short* tile, const unsigned short* src, int ld) {
    int tid = threadIdx.x;
#pragma unroll
    for (int i = 0; i < NCH; i++) {
        int ch  = tid + i * 256;
        int row = ch >> 3, c8 = ch & 7;
        uint4 u = *(const uint4*)(src + (size_t)row * ld + c8 * 8);
        *(uint4*)(tile + row * 64 + (((c8 ^ row) & 7) << 3)) = u;
    }
}

// ---------------------------------------------------------------------------
// Generic  C = A(Mx512) @ W(512x512)^T + bias,  64x64 block tile, 4 waves.
// MODE 0: bf16 out, head-major  [(b*H+h)*NR + n]*64 + d     (q / k projections)
// MODE 1: bf16 out, d-major     [(b*H+h)*64 + d]*NR + n     (v projection, transposed)
// MODE 2: fp32 out, row-major   [row*512 + n]               (final out projection)
// ABF: A is bf16 (else fp32, converted during staging). sh = log2(NR).
// ---------------------------------------------------------------------------
template<int MODE, bool ABF>
__global__ __launch_bounds__(256) void gemm512(const void* A, const float* W,
                                               const float* bias, void* dst, int sh)
{
    __shared__ unsigned short As[64 * 64];
    __shared__ unsigned short Bs[64 * 64];
    int r0 = blockIdx.x * 64;
    int n0 = blockIdx.y * 64;
    int tid = threadIdx.x;
    int w = tid >> 6, quad = (tid >> 4) & 3, l16 = tid & 15;
    f32x4 acc[4] = {};

    for (int k0 = 0; k0 < 512; k0 += 64) {
        __syncthreads();
        if (ABF) stage_bf<2>(As, (const unsigned short*)A + (size_t)r0 * 512 + k0, 512);
        else     stage_f32<2>(As, (const float*)A + (size_t)r0 * 512 + k0, 512);
        stage_f32<2>(Bs, W + (size_t)n0 * 512 + k0, 512);
        __syncthreads();
#pragma unroll
        for (int ks = 0; ks < 2; ks++) {
            bf16x8 af = ldfrag(As, 16 * w, 32 * ks);
#pragma unroll
            for (int nt = 0; nt < 4; nt++) {
                bf16x8 bfr = ldfrag(Bs, 16 * nt, 32 * ks);
                acc[nt] = __builtin_amdgcn_mfma_f32_16x16x32_bf16(af, bfr, acc[nt], 0, 0, 0);
            }
        }
    }

#pragma unroll
    for (int nt = 0; nt < 4; nt++) {
        int n = n0 + nt * 16 + l16;
        float bn = bias[n];
        int h = n >> 6, d = n & 63;
#pragma unroll
        for (int r = 0; r < 4; r++) {
            int row = r0 + w * 16 + quad * 4 + r;
            float val = acc[nt][r] + bn;
            if (MODE == 0) {
                int b = row >> sh, nloc = row & ((1 << sh) - 1);
                ((unsigned short*)dst)[((((size_t)(b * H_ + h) << sh) + nloc) << 6) + d] = f2bf(val);
            } else if (MODE == 1) {
                int b = row >> sh, nloc = row & ((1 << sh) - 1);
                ((unsigned short*)dst)[(((size_t)((b * H_ + h) * 64 + d)) << sh) + nloc] = f2bf(val);
            } else {
                ((float*)dst)[(size_t)row * 512 + n] = val;
            }
        }
    }
}

// Row-normalize 64-wide bf16 vectors in place (one wave per row).
__global__ __launch_bounds__(256) void normrows(unsigned short* x)
{
    int row  = blockIdx.x * 4 + (threadIdx.x >> 6);
    int lane = threadIdx.x & 63;
    size_t idx = (size_t)row * 64 + lane;
    float v = b2f(x[idx]);
    float s = v * v;
#pragma unroll
    for (int m = 1; m <= 32; m <<= 1) s += __shfl_xor(s, m, 64);
    float scale = 1.0f / fmaxf(sqrtf(s), 1e-20f);
    x[idx] = f2bf(v * scale);
}

// ---------------------------------------------------------------------------
// Scores + softmax: per (bh, 32-row t-tile). S = q̂ @ k̂^T  (cosine sims in [-1,1]),
// p = exp(S) kept in LDS as bf16 (32x2048 = 128 KB), then row-normalized and
// written once as fp32 att to d_out. No max-subtraction needed (|S| <= 1).
// ---------------------------------------------------------------------------
__global__ __launch_bounds__(256) void attn_scores(const unsigned short* qh,
                                                   const unsigned short* kh,
                                                   float* attout)
{
    __shared__ unsigned short Sp[32 * 2048];   // 128 KB
    __shared__ unsigned short Ks[128 * 64];    // 16 KB
    __shared__ unsigned short Qs[32 * 64];     // 4 KB
    __shared__ float invs[32];
    int bh = blockIdx.y;
    int t0 = blockIdx.x * 32;
    int tid = threadIdx.x;
    int w = tid >> 6, quad = (tid >> 4) & 3, l16 = tid & 15;

    stage_bf<1>(Qs, qh + ((size_t)bh * NT_ + t0) * 64, 64);

    for (int c0 = 0; c0 < NC_; c0 += 128) {
        __syncthreads();
        stage_bf<4>(Ks, kh + ((size_t)bh * NC_ + c0) * 64, 64);
        __syncthreads();
#pragma unroll
        for (int mt = 0; mt < 2; mt++) {
#pragma unroll
            for (int nt = 0; nt < 2; nt++) {
                f32x4 acc = {};
#pragma unroll
                for (int ks = 0; ks < 2; ks++) {
                    bf16x8 af  = ldfrag(Qs, 16 * mt, 32 * ks);
                    bf16x8 bfr = ldfrag(Ks, 32 * w + 16 * nt, 32 * ks);
                    acc = __builtin_amdgcn_mfma_f32_16x16x32_bf16(af, bfr, acc, 0, 0, 0);
                }
                int c = c0 + 32 * w + 16 * nt + l16;
#pragma unroll
                for (int r = 0; r < 4; r++) {
                    int tr = 16 * mt + quad * 4 + r;
                    Sp[tr * 2048 + c] = f2bf(__expf(acc[r]));
                }
            }
        }
    }
    __syncthreads();

    // row sums: 32 lanes per row, 64 strided elems each, shuffle-reduce in 32-groups
#pragma unroll
    for (int rp = 0; rp < 4; rp++) {
        int r  = rp * 8 + (tid >> 5);
        int cb = tid & 31;
        float s = 0.f;
        for (int i = 0; i < 64; i++) s += b2f(Sp[r * 2048 + cb + 32 * i]);
#pragma unroll
        for (int m = 1; m <= 16; m <<= 1) s += __shfl_xor(s, m, 64);
        if ((tid & 31) == 0) invs[r] = 1.0f / s;
    }
    __syncthreads();

    float* dst = attout + ((size_t)bh * NT_ + t0) * 2048;   // 32x2048 contiguous
    for (int idx = tid; idx < 32 * 2048; idx += 256) {
        int r = idx >> 11;
        dst[idx] = b2f(Sp[idx]) * invs[r];
    }
}

// ---------------------------------------------------------------------------
// O = att(512x2048, fp32 from d_out) @ V  via  Vt(64x2048, bf16 d-major).
// 64(t) x 64(d) block tile, K-chunks of 64 over c.
// ---------------------------------------------------------------------------
__global__ __launch_bounds__(256) void attn_out(const float* attout,
                                                const unsigned short* vt,
                                                unsigned short* oh)
{
    __shared__ unsigned short As[64 * 64];
    __shared__ unsigned short Bs[64 * 64];
    int bh = blockIdx.y;
    int t0 = blockIdx.x * 64;
    int tid = threadIdx.x;
    int w = tid >> 6, quad = (tid >> 4) & 3, l16 = tid & 15;
    f32x4 acc[4] = {};

    for (int c0 = 0; c0 < NC_; c0 += 64) {
        __syncthreads();
        stage_f32<2>(As, attout + ((size_t)bh * NT_ + t0) * 2048 + c0, 2048);
        stage_bf<2>(Bs, vt + (size_t)bh * 64 * NC_ + c0, NC_);
        __syncthreads();
#pragma unroll
        for (int ks = 0; ks < 2; ks++) {
            bf16x8 af = ldfrag(As, 16 * w, 32 * ks);
#pragma unroll
            for (int nt = 0; nt < 4; nt++) {
                bf16x8 bfr = ldfrag(Bs, 16 * nt, 32 * ks);
                acc[nt] = __builtin_amdgcn_mfma_f32_16x16x32_bf16(af, bfr, acc[nt], 0, 0, 0);
            }
        }
    }

    int b = bh >> 3, h = bh & 7;
#pragma unroll
    for (int nt = 0; nt < 4; nt++) {
        int d = nt * 16 + l16;
#pragma unroll
        for (int r = 0; r < 4; r++) {
            int t = t0 + 16 * w + quad * 4 + r;
            oh[(size_t)(b * NT_ + t) * 512 + h * 64 + d] = f2bf(acc[nt][r]);
        }
    }
}

// ---------------------------------------------------------------------------
extern "C" void kernel_launch(void* const* d_in, const int* in_sizes, int n_in,
                              void* d_out, int out_size, void* d_ws, size_t ws_size,
                              hipStream_t stream)
{
    (void)in_sizes; (void)n_in; (void)out_size; (void)ws_size;
    const float* queries = (const float*)d_in[0];
    const float* keys    = (const float*)d_in[1];
    const float* values  = (const float*)d_in[2];
    const float* W_At    = (const float*)d_in[3];
    const float* b_At    = (const float*)d_in[4];
    const float* W_Ac    = (const float*)d_in[5];
    const float* b_Ac    = (const float*)d_in[6];
    const float* W_Bc    = (const float*)d_in[7];
    const float* b_Bc    = (const float*)d_in[8];
    const float* W_R     = (const float*)d_in[9];
    const float* b_R     = (const float*)d_in[10];

    float* out0   = (float*)d_out;
    float* attout = out0 + (size_t)B_ * NT_ * EMB_;   // +2,097,152 floats

    // workspace (bf16 buffers), 40 MB total
    unsigned short* ws = (unsigned short*)d_ws;
    unsigned short* qh = ws;                          //  2,097,152 elems (B,H,NT,64)
    unsigned short* kh = qh + (size_t)2097152;        //  8,388,608 elems (B,H,NC,64)
    unsigned short* vt = kh + (size_t)8388608;        //  8,388,608 elems (B,H,64,NC)
    unsigned short* oh = vt + (size_t)8388608;        //  2,097,152 elems (B,NT,H*64)

    dim3 blk(256);

    // projections (fp32 inputs converted to bf16 during LDS staging)
    gemm512<0, false><<<dim3(4096 / 64, 8),  blk, 0, stream>>>(queries, W_At, b_At, qh, 9);
    gemm512<0, false><<<dim3(16384 / 64, 8), blk, 0, stream>>>(keys,    W_Ac, b_Ac, kh, 11);
    gemm512<1, false><<<dim3(16384 / 64, 8), blk, 0, stream>>>(values,  W_Bc, b_Bc, vt, 11);

    // normalize q,k rows so QK^T = cosine similarity
    normrows<<<(B_ * H_ * NT_) / 4, blk, 0, stream>>>(qh);
    normrows<<<(B_ * H_ * NC_) / 4, blk, 0, stream>>>(kh);

    // scores + softmax -> att (fp32, second output)
    attn_scores<<<dim3(NT_ / 32, B_ * H_), blk, 0, stream>>>(qh, kh, attout);

    // O = att @ V -> bf16 head-major
    attn_out<<<dim3(NT_ / 64, B_ * H_), blk, 0, stream>>>(attout, vt, oh);

    // out = O @ W_R^T + b_R (fp32, first output)
    gemm512<2, true><<<dim3(4096 / 64, 8), blk, 0, stream>>>(oh, W_R, b_R, out0, 0);
}

// Round 3
// 541.542 us; speedup vs baseline: 1.1720x; 1.1720x over previous
//
#include <hip/hip_runtime.h>

// Problem constants
#define B_   8
#define NT_  512
#define NC_  2048
#define EMB_ 512
#define H_   8
// DK = DV = 64

typedef __attribute__((ext_vector_type(8))) short bf16x8;
typedef __attribute__((ext_vector_type(4))) float f32x4;

__device__ __forceinline__ unsigned short f2bf(float x) {
    unsigned u = __float_as_uint(x);
    u += 0x7fffu + ((u >> 16) & 1u);          // RNE
    return (unsigned short)(u >> 16);
}
__device__ __forceinline__ float b2f(unsigned short h) {
    return __uint_as_float(((unsigned)h) << 16);
}

// XOR-swizzled LDS tile index: rows of 64 bf16, 8-elem (16B) granules.
__device__ __forceinline__ int swz(int row, int col) {
    return row * 64 + ((((col >> 3) ^ row) & 7) << 3) + (col & 7);
}

// MFMA operand fragment from a swizzled 64-col tile:
// elem j of lane L holds T[rowbase + (L&15)][kq + (L>>4)*8 + j]
__device__ __forceinline__ bf16x8 ldfrag(const unsigned short* t, int rowbase, int kq) {
    int lane = threadIdx.x & 63;
    int m = rowbase + (lane & 15);
    int k = kq + ((lane >> 4) << 3);
    return *(const bf16x8*)(t + swz(m, k));
}

// Stage a 64-col x (NCH*32)-row tile into swizzled LDS from fp32 global (cvt bf16).
template<int NCH>
__device__ __forceinline__ void stage_f32(unsigned short* tile, const float* src, int ld) {
    int tid = threadIdx.x;
#pragma unroll
    for (int i = 0; i < NCH; i++) {
        int ch  = tid + i * 256;
        int row = ch >> 3, c8 = ch & 7;
        const float4* p = (const float4*)(src + (size_t)row * ld + c8 * 8);
        float4 a = p[0], b = p[1];
        uint4 u;
        u.x = (unsigned)f2bf(a.x) | ((unsigned)f2bf(a.y) << 16);
        u.y = (unsigned)f2bf(a.z) | ((unsigned)f2bf(a.w) << 16);
        u.z = (unsigned)f2bf(b.x) | ((unsigned)f2bf(b.y) << 16);
        u.w = (unsigned)f2bf(b.z) | ((unsigned)f2bf(b.w) << 16);
        *(uint4*)(tile + row * 64 + (((c8 ^ row) & 7) << 3)) = u;
    }
}
// Same, from bf16 global.
template<int NCH>
__device__ __forceinline__ void stage_bf(unsigned short* tile, const unsigned short* src, int ld) {
    int tid = threadIdx.x;
#pragma unroll
    for (int i = 0; i < NCH; i++) {
        int ch  = tid + i * 256;
        int row = ch >> 3, c8 = ch & 7;
        uint4 u = *(const uint4*)(src + (size_t)row * ld + c8 * 8);
        *(uint4*)(tile + row * 64 + (((c8 ^ row) & 7) << 3)) = u;
    }
}

// ---------------------------------------------------------------------------
// C = A(Mx512) @ W(512x512)^T + bias, 64x64 block tile, 4 waves.
// MODE 0: bf16 out, head-major, ROW-NORMALIZED (q/k projections; 64-n tile == one head)
// MODE 1: bf16 out, d-major transposed (v projection)
// MODE 2: fp32 out, row-major (final out projection)
// ---------------------------------------------------------------------------
template<int MODE, bool ABF>
__global__ __launch_bounds__(256) void gemm512(const void* A, const float* W,
                                               const float* bias, void* dst, int sh)
{
    __shared__ unsigned short As[64 * 64];
    __shared__ unsigned short Bs[64 * 64];
    int r0 = blockIdx.x * 64;
    int n0 = blockIdx.y * 64;
    int tid = threadIdx.x;
    int w = tid >> 6, quad = (tid >> 4) & 3, l16 = tid & 15;
    f32x4 acc[4] = {};

    for (int k0 = 0; k0 < 512; k0 += 64) {
        __syncthreads();
        if (ABF) stage_bf<2>(As, (const unsigned short*)A + (size_t)r0 * 512 + k0, 512);
        else     stage_f32<2>(As, (const float*)A + (size_t)r0 * 512 + k0, 512);
        stage_f32<2>(Bs, W + (size_t)n0 * 512 + k0, 512);
        __syncthreads();
#pragma unroll
        for (int ks = 0; ks < 2; ks++) {
            bf16x8 af = ldfrag(As, 16 * w, 32 * ks);
#pragma unroll
            for (int nt = 0; nt < 4; nt++) {
                bf16x8 bfr = ldfrag(Bs, 16 * nt, 32 * ks);
                acc[nt] = __builtin_amdgcn_mfma_f32_16x16x32_bf16(af, bfr, acc[nt], 0, 0, 0);
            }
        }
    }

    float vals[4][4];
    float bn[4];
#pragma unroll
    for (int nt = 0; nt < 4; nt++) bn[nt] = bias[n0 + nt * 16 + l16];
#pragma unroll
    for (int nt = 0; nt < 4; nt++)
#pragma unroll
        for (int r = 0; r < 4; r++) vals[nt][r] = acc[nt][r] + bn[nt];

    if (MODE == 0) {
        // fused row-normalize: row's 64 d-values live across l16 group x 4 nt regs
#pragma unroll
        for (int r = 0; r < 4; r++) {
            float ss = 0.f;
#pragma unroll
            for (int nt = 0; nt < 4; nt++) ss += vals[nt][r] * vals[nt][r];
#pragma unroll
            for (int m = 1; m <= 8; m <<= 1) ss += __shfl_xor(ss, m, 64);
            float sc = rsqrtf(fmaxf(ss, 1e-24f));
#pragma unroll
            for (int nt = 0; nt < 4; nt++) vals[nt][r] *= sc;
        }
    }

#pragma unroll
    for (int nt = 0; nt < 4; nt++) {
        int n = n0 + nt * 16 + l16;
        int h = n >> 6, d = n & 63;
#pragma unroll
        for (int r = 0; r < 4; r++) {
            int row = r0 + w * 16 + quad * 4 + r;
            float val = vals[nt][r];
            if (MODE == 0) {
                int b = row >> sh, nloc = row & ((1 << sh) - 1);
                ((unsigned short*)dst)[((((size_t)(b * H_ + h) << sh) + nloc) << 6) + d] = f2bf(val);
            } else if (MODE == 1) {
                int b = row >> sh, nloc = row & ((1 << sh) - 1);
                ((unsigned short*)dst)[(((size_t)((b * H_ + h) * 64 + d)) << sh) + nloc] = f2bf(val);
            } else {
                ((float*)dst)[(size_t)row * 512 + n] = val;
            }
        }
    }
}

// ---------------------------------------------------------------------------
// Fused attention: per (bh, 32-row t-tile).
//   S = q̂ @ k̂^T (cosine sims, |S|<=1 so exp needs no max-subtract)
//   Sp = exp(S) as bf16 in LDS (32 x 2048, padded stride 2056)
//   invs = 1/rowsum;  att = Sp*invs -> d_out (nontemporal, 268 MB stream)
//   O = (Sp @ Vt^T) * invs -> bf16 head-major oh
// ---------------------------------------------------------------------------
#define SPAD 2056   // Sp row stride in shorts (pad 8: stride%32dw==4 -> <=2-way banks)

__global__ __launch_bounds__(256) void attn_fused(const unsigned short* qh,
                                                  const unsigned short* kh,
                                                  const unsigned short* vt,
                                                  float* attout,
                                                  unsigned short* oh)
{
    __shared__ unsigned short Sp[32 * SPAD];   // 131584 B
    __shared__ unsigned short Ks[128 * 64];    // 16 KB (reused as V-stage in PV phase)
    __shared__ unsigned short Qs[32 * 64];     // 4 KB
    __shared__ float invs[32];
    int bh = blockIdx.y;
    int t0 = blockIdx.x * 32;
    int tid = threadIdx.x;
    int w = tid >> 6, quad = (tid >> 4) & 3, l16 = tid & 15;

    stage_bf<1>(Qs, qh + ((size_t)bh * NT_ + t0) * 64, 64);
    __syncthreads();
    // q fragments are invariant over the c-loop: hoist (4 x b128)
    bf16x8 qf[2][2];
#pragma unroll
    for (int mt = 0; mt < 2; mt++)
#pragma unroll
        for (int ks = 0; ks < 2; ks++) qf[mt][ks] = ldfrag(Qs, 16 * mt, 32 * ks);

    // ---- phase 1: S = qk^T, Sp = exp(S) ----
    for (int c0 = 0; c0 < NC_; c0 += 128) {
        __syncthreads();
        stage_bf<4>(Ks, kh + ((size_t)bh * NC_ + c0) * 64, 64);
        __syncthreads();
#pragma unroll
        for (int nt = 0; nt < 2; nt++) {
#pragma unroll
            for (int mt = 0; mt < 2; mt++) {
                f32x4 acc = {};
#pragma unroll
                for (int ks = 0; ks < 2; ks++) {
                    bf16x8 bfr = ldfrag(Ks, 32 * w + 16 * nt, 32 * ks);
                    acc = __builtin_amdgcn_mfma_f32_16x16x32_bf16(qf[mt][ks], bfr, acc, 0, 0, 0);
                }
                int c = c0 + 32 * w + 16 * nt + l16;
#pragma unroll
                for (int r = 0; r < 4; r++) {
                    int tr = 16 * mt + quad * 4 + r;
                    Sp[tr * SPAD + c] = f2bf(__expf(acc[r]));
                }
            }
        }
    }
    __syncthreads();

    // ---- phase 2: row sums (vectorized b128 reads; 8 threads per row) ----
    {
        int r = tid >> 3, p = tid & 7;
        float s = 0.f;
#pragma unroll 4
        for (int i = 0; i < 32; i++) {
            uint4 u = *(const uint4*)(Sp + r * SPAD + p * 8 + 64 * i);
            s += b2f((unsigned short)(u.x)) + b2f((unsigned short)(u.x >> 16))
               + b2f((unsigned short)(u.y)) + b2f((unsigned short)(u.y >> 16))
               + b2f((unsigned short)(u.z)) + b2f((unsigned short)(u.z >> 16))
               + b2f((unsigned short)(u.w)) + b2f((unsigned short)(u.w >> 16));
        }
#pragma unroll
        for (int m = 1; m <= 4; m <<= 1) s += __shfl_xor(s, m, 64);
        if (p == 0) invs[r] = 1.0f / s;
    }
    __syncthreads();

    // ---- phase 3: att write + O = Sp @ Vt^T (V streamed through Ks area) ----
    int wr_r = tid >> 3, wr_p = tid & 7;                 // att-write assignment
    float inv_wr = invs[wr_r];
    float* attbase = attout + ((size_t)bh * NT_ + t0) * 2048;
    f32x4 oacc[2] = {};                                   // rows 16*mt.., d-col 16*w+l16

    for (int c0 = 0; c0 < NC_; c0 += 64) {
        __syncthreads();
        stage_bf<2>(Ks, vt + (size_t)bh * 64 * NC_ + c0, NC_);
        __syncthreads();
#pragma unroll
        for (int ks = 0; ks < 2; ks++) {
            bf16x8 bfr = ldfrag(Ks, 16 * w, 32 * ks);    // wave w owns d-cols 16w..16w+16
#pragma unroll
            for (int mt = 0; mt < 2; mt++) {
                bf16x8 af;
                {   // A-frag from Sp (unswizzled, padded stride)
                    int m = 16 * mt + (tid & 15);
                    int k = c0 + 32 * ks + (((tid >> 4) & 3) << 3);
                    af = *(const bf16x8*)(Sp + m * SPAD + k);
                }
                oacc[mt] = __builtin_amdgcn_mfma_f32_16x16x32_bf16(af, bfr, oacc[mt], 0, 0, 0);
            }
        }
        // stream this chunk of att out (row wr_r, 8 consecutive floats x2)
        {
            uint4 u = *(const uint4*)(Sp + wr_r * SPAD + c0 + wr_p * 8);
            f32x4 f0, f1;
            f0.x = b2f((unsigned short)(u.x)) * inv_wr;
            f0.y = b2f((unsigned short)(u.x >> 16)) * inv_wr;
            f0.z = b2f((unsigned short)(u.y)) * inv_wr;
            f0.w = b2f((unsigned short)(u.y >> 16)) * inv_wr;
            f1.x = b2f((unsigned short)(u.z)) * inv_wr;
            f1.y = b2f((unsigned short)(u.z >> 16)) * inv_wr;
            f1.z = b2f((unsigned short)(u.w)) * inv_wr;
            f1.w = b2f((unsigned short)(u.w >> 16)) * inv_wr;
            f32x4* dstp = (f32x4*)(attbase + (size_t)wr_r * 2048 + c0 + wr_p * 8);
            __builtin_nontemporal_store(f0, dstp);
            __builtin_nontemporal_store(f1, dstp + 1);
        }
    }

    // ---- epilogue: scale O rows by invs, store bf16 head-major ----
    int b = bh >> 3, h = bh & 7;
    int d = 16 * w + l16;
#pragma unroll
    for (int mt = 0; mt < 2; mt++) {
#pragma unroll
        for (int r = 0; r < 4; r++) {
            int t = 16 * mt + quad * 4 + r;
            float val = oacc[mt][r] * invs[t];
            oh[(size_t)(b * NT_ + t0 + t) * 512 + h * 64 + d] = f2bf(val);
        }
    }
}

// ---------------------------------------------------------------------------
extern "C" void kernel_launch(void* const* d_in, const int* in_sizes, int n_in,
                              void* d_out, int out_size, void* d_ws, size_t ws_size,
                              hipStream_t stream)
{
    (void)in_sizes; (void)n_in; (void)out_size; (void)ws_size;
    const float* queries = (const float*)d_in[0];
    const float* keys    = (const float*)d_in[1];
    const float* values  = (const float*)d_in[2];
    const float* W_At    = (const float*)d_in[3];
    const float* b_At    = (const float*)d_in[4];
    const float* W_Ac    = (const float*)d_in[5];
    const float* b_Ac    = (const float*)d_in[6];
    const float* W_Bc    = (const float*)d_in[7];
    const float* b_Bc    = (const float*)d_in[8];
    const float* W_R     = (const float*)d_in[9];
    const float* b_R     = (const float*)d_in[10];

    float* out0   = (float*)d_out;
    float* attout = out0 + (size_t)B_ * NT_ * EMB_;

    unsigned short* ws = (unsigned short*)d_ws;
    unsigned short* qh = ws;                          // (B,H,NT,64) bf16, normalized
    unsigned short* kh = qh + (size_t)2097152;        // (B,H,NC,64) bf16, normalized
    unsigned short* vt = kh + (size_t)8388608;        // (B,H,64,NC) bf16 d-major
    unsigned short* oh = vt + (size_t)8388608;        // (B,NT,H*64) bf16

    dim3 blk(256);

    // projections (q/k with fused row-normalization in the epilogue)
    gemm512<0, false><<<dim3(4096 / 64, 8),  blk, 0, stream>>>(queries, W_At, b_At, qh, 9);
    gemm512<0, false><<<dim3(16384 / 64, 8), blk, 0, stream>>>(keys,    W_Ac, b_Ac, kh, 11);
    gemm512<1, false><<<dim3(16384 / 64, 8), blk, 0, stream>>>(values,  W_Bc, b_Bc, vt, 11);

    // fused scores + softmax + att-write + P@V
    attn_fused<<<dim3(NT_ / 32, B_ * H_), blk, 0, stream>>>(qh, kh, vt, attout, oh);

    // out = O @ W_R^T + b_R
    gemm512<2, true><<<dim3(4096 / 64, 8), blk, 0, stream>>>(oh, W_R, b_R, out0, 0);
}